// Round 1
// 357.630 us; speedup vs baseline: 1.0391x; 1.0391x over previous
//
#include <hip/hip_runtime.h>
#include <math.h>

// Problem constants (fixed by reference: B=8, Cl=128, Ch=64, Hl=Wl=96, Hh=Wh=192, CROSS=12)
#define NB 8
#define CL 128
#define CH 64
#define HL 96
#define WL 96
#define PL (HL*WL)          // 9216
#define HH 192
#define WH 192
#define PH (HH*WH)          // 36864
#define NS 144              // CROSS*CROSS
#define BN_S 0.9999950000374997f   // 1/sqrt(1+1e-5)
#define INV12 (1.0f/12.0f)         // S^-0.5

typedef __attribute__((ext_vector_type(8))) short bf16x8;
typedef __attribute__((ext_vector_type(4))) float f32x4;
#define MFMA16(a,b,c) __builtin_amdgcn_mfma_f32_16x16x32_bf16(a,b,c,0,0,0)

__device__ __forceinline__ float gelu_exact(float x){
    return 0.5f*x*(1.0f + erff(x*0.7071067811865475f));
}
__device__ __forceinline__ short f2bf(float f){
    union { float f; unsigned u; } v; v.f = f;
    unsigned r = v.u + 0x7FFFu + ((v.u >> 16) & 1u);   // round-nearest-even
    return (short)(r >> 16);
}

// ---------------- K1: x_l2 = x_l + mlp_l(x_l)  [MFMA bf16, 64 px/block, 4 waves x 16 px] ----------
__global__ __launch_bounds__(256) void k_mlp_l(
    const float* __restrict__ xl, const float* __restrict__ w1, const float* __restrict__ b1,
    const float* __restrict__ w2, const float* __restrict__ b2, float* __restrict__ xl2)
{
    __shared__ short Wb[128*136];   // W1 then W2
    __shared__ short Xb[64*136];    // Xt then Ht
    __shared__ float bS[256];       // b1 | b2
    const int tid = threadIdx.x;
    const int b   = blockIdx.x / (PL/64);
    const int hw0 = (blockIdx.x % (PL/64)) * 64;
    const float* xb = xl + (size_t)b*CL*PL + hw0;
    #pragma unroll
    for (int i=0;i<64;i++){ int idx=i*256+tid; Wb[(idx>>7)*136 + (idx&127)] = f2bf(w1[idx]); }
    #pragma unroll
    for (int i=0;i<32;i++){ int idx=i*256+tid; int c=idx>>6, p=idx&63;
        Xb[p*136+c] = f2bf(xb[(size_t)c*PL + p]); }
    if (tid < 128) bS[tid] = b1[tid]; else bS[tid] = b2[tid-128];
    __syncthreads();
    const int w = tid>>6, lane = tid&63, l16 = lane&15, q = lane>>4;
    const int pw = w*16;
    float hv[8][4];
    #pragma unroll
    for (int mt=0; mt<8; mt++){
        f32x4 acc = {0.f,0.f,0.f,0.f};
        #pragma unroll
        for (int k=0;k<4;k++){
            bf16x8 af = *(const bf16x8*)&Wb[(mt*16+l16)*136 + k*32 + q*8];
            bf16x8 bf = *(const bf16x8*)&Xb[(pw+l16)*136 + k*32 + q*8];
            acc = MFMA16(af, bf, acc);
        }
        #pragma unroll
        for (int r=0;r<4;r++) hv[mt][r] = gelu_exact(acc[r] + bS[mt*16+q*4+r]);
    }
    #pragma unroll
    for (int mt=0;mt<8;mt++)
        #pragma unroll
        for (int r=0;r<4;r++)
            Xb[(pw+l16)*136 + mt*16+q*4+r] = f2bf(hv[mt][r]);
    __syncthreads();
    #pragma unroll
    for (int i=0;i<64;i++){ int idx=i*256+tid; Wb[(idx>>7)*136 + (idx&127)] = f2bf(w2[idx]); }
    __syncthreads();
    float* yb = xl2 + (size_t)b*CL*PL + hw0;
    #pragma unroll
    for (int mt=0; mt<8; mt++){
        f32x4 acc = {0.f,0.f,0.f,0.f};
        #pragma unroll
        for (int k=0;k<4;k++){
            bf16x8 af = *(const bf16x8*)&Wb[(mt*16+l16)*136 + k*32 + q*8];
            bf16x8 bf = *(const bf16x8*)&Xb[(pw+l16)*136 + k*32 + q*8];
            acc = MFMA16(af, bf, acc);
        }
        #pragma unroll
        for (int r=0;r<4;r++){
            int o = mt*16 + q*4 + r;
            size_t off = (size_t)o*PL + pw + l16;
            yb[off] = acc[r] + bS[128+o] + xb[off];
        }
    }
}

// ---------------- K2: xc = relu(bn(conv1x1(x_l2, conv_w)))  [MFMA bf16] ----------------
__global__ __launch_bounds__(256) void k_conv_l(
    const float* __restrict__ xl2, const float* __restrict__ cw,
    const float* __restrict__ bng, const float* __restrict__ bnb, float* __restrict__ xc)
{
    __shared__ short Wb[64*136];
    __shared__ short Xb[64*136];
    const int tid = threadIdx.x;
    const int b   = blockIdx.x / (PL/64);
    const int hw0 = (blockIdx.x % (PL/64)) * 64;
    const float* xb = xl2 + (size_t)b*CL*PL + hw0;
    #pragma unroll
    for (int i=0;i<32;i++){ int idx=i*256+tid; Wb[(idx>>7)*136 + (idx&127)] = f2bf(cw[idx]); }
    #pragma unroll
    for (int i=0;i<32;i++){ int idx=i*256+tid; int c=idx>>6, p=idx&63;
        Xb[p*136+c] = f2bf(xb[(size_t)c*PL + p]); }
    __syncthreads();
    const int w = tid>>6, lane = tid&63, l16 = lane&15, q = lane>>4;
    const int pw = w*16;
    float* yb = xc + (size_t)b*CH*PL + hw0;
    #pragma unroll
    for (int mt=0; mt<4; mt++){
        f32x4 acc = {0.f,0.f,0.f,0.f};
        #pragma unroll
        for (int k=0;k<4;k++){
            bf16x8 af = *(const bf16x8*)&Wb[(mt*16+l16)*136 + k*32 + q*8];
            bf16x8 bf = *(const bf16x8*)&Xb[(pw+l16)*136 + k*32 + q*8];
            acc = MFMA16(af, bf, acc);
        }
        #pragma unroll
        for (int r=0;r<4;r++){
            int o = mt*16 + q*4 + r;
            float sc = bng[o]*BN_S, bb = bnb[o];
            yb[(size_t)o*PL + pw + l16] = fmaxf(sc*acc[r] + bb, 0.f);
        }
    }
}

// ---------------- K4a: pooled[b,c,s] = max_{8x8}( bn_kv(x_l2) ) ----------------
__global__ __launch_bounds__(192) void k_pool(
    const float* __restrict__ xl2, const float* __restrict__ g, const float* __restrict__ bta,
    float* __restrict__ pooled)
{
    const int plane = blockIdx.x;      // b*CL + c
    const int tid = threadIdx.x;
    if (tid >= NS) return;
    const int c = plane & (CL-1);
    const float sc = g[c]*BN_S;
    const float tc = bta[c];
    const int i = tid/12, j = tid%12;
    const float* base = xl2 + (size_t)plane*PL + (size_t)i*8*WL + j*8;
    float m = -3.4e38f;
    #pragma unroll
    for (int dy=0;dy<8;dy++){
        const float* rr = base + dy*WL;
        #pragma unroll
        for (int dx=0;dx<8;dx++) m = fmaxf(m, sc*rr[dx]+tc);
    }
    pooled[(size_t)plane*NS + tid] = m;
}

// ---------------- K4b: kv proj, thread per (o,s), o in 0..127 (2*Ch=128 rows): 576 blocks --------
// keg[b][s][ch] = kv_k * ng[ch]*BN_S/12 ; biasg[b][s] += kv_k * nb[ch]/12 ; vg[b][s][ch] = kv_v
__global__ __launch_bounds__(256) void k_kv(
    const float* __restrict__ pooled, const float* __restrict__ kvw, const float* __restrict__ kvb,
    const float* __restrict__ ng, const float* __restrict__ nb,
    float* __restrict__ keg, float* __restrict__ vg, float* __restrict__ biasg)
{
    const int t = blockIdx.x*256 + threadIdx.x;     // over NB*128*NS = 147456
    const int s = t % NS;
    const int r = t / NS;
    const int o = r & 127;        // 2*Ch = 128 output rows
    const int b = r >> 7;
    const float* P = pooled + (size_t)b*CL*NS + s;
    const float* W = kvw + (size_t)o*CL;
    float acc = kvb[o];
    #pragma unroll 4
    for (int c=0;c<CL;c++) acc = fmaf(W[c], P[(size_t)c*NS], acc);
    if (o < CH){
        keg[((size_t)b*NS+s)*CH + o] = acc * (ng[o]*(BN_S*INV12));
        atomicAdd(&biasg[b*NS+s], acc * (nb[o]*INV12));
    } else {
        vg[((size_t)b*NS+s)*CH + (o-CH)] = acc;
    }
}

// ---------------- K5: cross-attention, FUSED with upsample residual ----------------
// xh2 = xh + bilinear_up2x(xc) computed inline (never materialized);
// out = xh2 + attn(bn(xh2))·V.  Each 64-px block lies within ONE output row
// (WH=192 = 3*64), so row-side bilinear weights are block-uniform.
__global__ __launch_bounds__(256) void k_attn(
    const float* __restrict__ xh, const float* __restrict__ xc,
    const float* __restrict__ keg, const float* __restrict__ vg,
    const float* __restrict__ biasg, float* __restrict__ out)
{
    __shared__ short KVb[64*168];   // Ke (144x72) then Vt (64x168)
    __shared__ short Xb[64*72];     // Xt (bf16 of xh2 tile)
    __shared__ short Pt[64*168];    // P transposed [p][s], K padded to 160
    __shared__ float bS[NS];
    const int tid = threadIdx.x;
    const int b   = blockIdx.x / (PH/64);
    const int hw0 = (blockIdx.x % (PH/64)) * 64;
    const int y   = hw0 / WH;          // block-uniform output row
    const int xst = hw0 % WH;          // 0, 64 or 128
    // row-side bilinear weights (block-uniform)
    const int   lyr = (y>>1) - ((y&1)^1);
    const float fy  = (y&1) ? 0.25f : 0.75f;
    const int   y0i = lyr<0?0:lyr;
    const int   y1i = (lyr+1>HL-1)?(HL-1):(lyr+1);

    const float* xb  = xh + (size_t)b*CH*PH + hw0;
    const float* xcb = xc + (size_t)b*CH*PL;
    const float* keb = keg + (size_t)b*NS*CH;
    #pragma unroll
    for (int i=0;i<36;i++){ int idx=i*256+tid; KVb[(idx>>6)*72 + (idx&63)] = f2bf(keb[idx]); }
    // stage Xt = bf16( xh + bilerp(xc) ), transposed [p][c]
    #pragma unroll
    for (int i=0;i<16;i++){
        int idx=i*256+tid; int c=idx>>6, p=idx&63;
        int xo = xst + p;
        int lx = (xo>>1) - ((xo&1)^1);
        float fx = (xo&1) ? 0.25f : 0.75f;
        int x0i = lx<0?0:lx; int x1i = (lx+1>WL-1)?(WL-1):(lx+1);
        const float* s = xcb + (size_t)c*PL;
        float v00 = s[y0i*WL+x0i], v01 = s[y0i*WL+x1i];
        float v10 = s[y1i*WL+x0i], v11 = s[y1i*WL+x1i];
        float top = v00 + fx*(v01-v00);
        float bot = v10 + fx*(v11-v10);
        float up  = top + fy*(bot-top);
        Xb[p*72+c] = f2bf(xb[(size_t)c*PH + p] + up);
    }
    if (tid < NS) bS[tid] = biasg[b*NS+tid];
    #pragma unroll
    for (int i=0;i<4;i++){ int idx=i*256+tid; Pt[(idx>>4)*168 + 144 + (idx&15)] = 0; }
    __syncthreads();
    const int w = tid>>6, lane = tid&63, l16 = lane&15, q = lane>>4;
    const int pw = w*16;
    float ev[9][4];
    float mloc = -3.4e38f;
    #pragma unroll
    for (int st=0; st<9; st++){
        f32x4 acc = {0.f,0.f,0.f,0.f};
        #pragma unroll
        for (int k=0;k<2;k++){
            bf16x8 af = *(const bf16x8*)&KVb[(st*16+l16)*72 + k*32 + q*8];
            bf16x8 bf = *(const bf16x8*)&Xb[(pw+l16)*72 + k*32 + q*8];
            acc = MFMA16(af, bf, acc);
        }
        #pragma unroll
        for (int r=0;r<4;r++){
            float v = acc[r] + bS[st*16+q*4+r];
            ev[st][r] = v; mloc = fmaxf(mloc, v);
        }
    }
    mloc = fmaxf(mloc, __shfl_xor(mloc,16));
    mloc = fmaxf(mloc, __shfl_xor(mloc,32));
    float sloc = 0.f;
    #pragma unroll
    for (int st=0;st<9;st++)
        #pragma unroll
        for (int r=0;r<4;r++){ float e = __expf(ev[st][r]-mloc); ev[st][r]=e; sloc+=e; }
    sloc += __shfl_xor(sloc,16);
    sloc += __shfl_xor(sloc,32);
    const float rs = 1.f/sloc;
    #pragma unroll
    for (int st=0;st<9;st++)
        #pragma unroll
        for (int r=0;r<4;r++)
            Pt[(pw+l16)*168 + st*16+q*4+r] = f2bf(ev[st][r]);
    __syncthreads();                       // Ke fully consumed; P visible
    const float* vb = vg + (size_t)b*NS*CH;
    #pragma unroll
    for (int i=0;i<36;i++){ int idx=i*256+tid; int s=idx>>6, c=idx&63;
        KVb[c*168 + s] = f2bf(vb[idx]); }
    #pragma unroll
    for (int i=0;i<4;i++){ int idx=i*256+tid; KVb[(idx>>4)*168 + 144 + (idx&15)] = 0; }
    __syncthreads();
    float* ob = out + (size_t)b*CH*PH + hw0;
    // per-thread pixel is fixed: recompute its bilinear weights once
    const int px  = pw + l16;
    const int xo  = xst + px;
    const int lxe = (xo>>1) - ((xo&1)^1);
    const float fxe = (xo&1) ? 0.25f : 0.75f;
    const int x0e = lxe<0?0:lxe;
    const int x1e = (lxe+1>WL-1)?(WL-1):(lxe+1);
    #pragma unroll
    for (int mt=0; mt<4; mt++){
        f32x4 acc = {0.f,0.f,0.f,0.f};
        #pragma unroll
        for (int k=0;k<5;k++){
            bf16x8 af = *(const bf16x8*)&KVb[(mt*16+l16)*168 + k*32 + q*8];
            bf16x8 bf = *(const bf16x8*)&Pt[(pw+l16)*168 + k*32 + q*8];
            acc = MFMA16(af, bf, acc);
        }
        #pragma unroll
        for (int r=0;r<4;r++){
            int ch = mt*16 + q*4 + r;
            const float* s = xcb + (size_t)ch*PL;
            float v00 = s[y0i*WL+x0e], v01 = s[y0i*WL+x1e];
            float v10 = s[y1i*WL+x0e], v11 = s[y1i*WL+x1e];
            float top = v00 + fxe*(v01-v00);
            float bot = v10 + fxe*(v11-v10);
            float up  = top + fy*(bot-top);
            size_t off = (size_t)ch*PH + px;
            ob[off] = (xb[off] + up) + acc[r]*rs;   // identical fp32 expr as staging
        }
    }
}

// ---------------- K6: d_out += mlp_h(d_out)  [MFMA bf16, in-place] ----------------
__global__ __launch_bounds__(256) void k_mlp_h(
    float* __restrict__ xh, const float* __restrict__ w1, const float* __restrict__ b1,
    const float* __restrict__ w2, const float* __restrict__ b2)
{
    __shared__ short Wb[64*72];
    __shared__ short Xb[64*72];
    __shared__ float bS[128];
    const int tid = threadIdx.x;
    const int b   = blockIdx.x / (PH/64);
    const int hw0 = (blockIdx.x % (PH/64)) * 64;
    float* xb = xh + (size_t)b*CH*PH + hw0;
    #pragma unroll
    for (int i=0;i<16;i++){ int idx=i*256+tid; Wb[(idx>>6)*72 + (idx&63)] = f2bf(w1[idx]); }
    #pragma unroll
    for (int i=0;i<16;i++){ int idx=i*256+tid; int c=idx>>6, p=idx&63;
        Xb[p*72+c] = f2bf(xb[(size_t)c*PH + p]); }
    if (tid < 64) bS[tid] = b1[tid]; else if (tid < 128) bS[tid] = b2[tid-64];
    __syncthreads();
    const int w = tid>>6, lane = tid&63, l16 = lane&15, q = lane>>4;
    const int pw = w*16;
    float hv[4][4];
    #pragma unroll
    for (int mt=0; mt<4; mt++){
        f32x4 acc = {0.f,0.f,0.f,0.f};
        #pragma unroll
        for (int k=0;k<2;k++){
            bf16x8 af = *(const bf16x8*)&Wb[(mt*16+l16)*72 + k*32 + q*8];
            bf16x8 bf = *(const bf16x8*)&Xb[(pw+l16)*72 + k*32 + q*8];
            acc = MFMA16(af, bf, acc);
        }
        #pragma unroll
        for (int r=0;r<4;r++) hv[mt][r] = gelu_exact(acc[r] + bS[mt*16+q*4+r]);
    }
    #pragma unroll
    for (int mt=0;mt<4;mt++)
        #pragma unroll
        for (int r=0;r<4;r++)
            Xb[(pw+l16)*72 + mt*16+q*4+r] = f2bf(hv[mt][r]);
    __syncthreads();
    #pragma unroll
    for (int i=0;i<16;i++){ int idx=i*256+tid; Wb[(idx>>6)*72 + (idx&63)] = f2bf(w2[idx]); }
    __syncthreads();
    #pragma unroll
    for (int mt=0; mt<4; mt++){
        f32x4 acc = {0.f,0.f,0.f,0.f};
        #pragma unroll
        for (int k=0;k<2;k++){
            bf16x8 af = *(const bf16x8*)&Wb[(mt*16+l16)*72 + k*32 + q*8];
            bf16x8 bf = *(const bf16x8*)&Xb[(pw+l16)*72 + k*32 + q*8];
            acc = MFMA16(af, bf, acc);
        }
        #pragma unroll
        for (int r=0;r<4;r++){
            int o = mt*16 + q*4 + r;
            size_t off = (size_t)o*PH + pw + l16;
            xb[off] = acc[r] + bS[64+o] + xb[off];
        }
    }
}

extern "C" void kernel_launch(void* const* d_in, const int* in_sizes, int n_in,
                              void* d_out, int out_size, void* d_ws, size_t ws_size,
                              hipStream_t stream)
{
    const float* xl    = (const float*)d_in[0];
    const float* xh    = (const float*)d_in[1];
    const float* ml_w1 = (const float*)d_in[2];
    const float* ml_b1 = (const float*)d_in[3];
    const float* ml_w2 = (const float*)d_in[4];
    const float* ml_b2 = (const float*)d_in[5];
    const float* cw    = (const float*)d_in[6];
    const float* cbg   = (const float*)d_in[7];
    const float* cbb   = (const float*)d_in[8];
    const float* kbg   = (const float*)d_in[9];
    const float* kbb   = (const float*)d_in[10];
    const float* kvw   = (const float*)d_in[11];
    const float* kvb   = (const float*)d_in[12];
    const float* ng    = (const float*)d_in[13];
    const float* nb    = (const float*)d_in[14];
    const float* mh_w1 = (const float*)d_in[15];
    const float* mh_b1 = (const float*)d_in[16];
    const float* mh_w2 = (const float*)d_in[17];
    const float* mh_b2 = (const float*)d_in[18];
    float* out = (float*)d_out;

    float* ws     = (float*)d_ws;
    float* xl2    = ws;                          // NB*CL*PL
    float* xc     = xl2    + (size_t)NB*CL*PL;   // NB*CH*PL
    float* pooled = xc     + (size_t)NB*CH*PL;   // NB*CL*NS
    float* keg    = pooled + (size_t)NB*CL*NS;   // NB*NS*CH
    float* vg     = keg    + (size_t)NB*NS*CH;   // NB*NS*CH
    float* biasg  = vg     + (size_t)NB*NS*CH;   // NB*NS

    k_mlp_l<<<dim3(NB*PL/64), dim3(256), 0, stream>>>(xl, ml_w1, ml_b1, ml_w2, ml_b2, xl2);
    k_conv_l<<<dim3(NB*PL/64), dim3(256), 0, stream>>>(xl2, cw, cbg, cbb, xc);
    k_pool<<<dim3(NB*CL), dim3(192), 0, stream>>>(xl2, kbg, kbb, pooled);
    hipMemsetAsync(biasg, 0, (size_t)NB*NS*sizeof(float), stream);
    k_kv<<<dim3((NB*128*NS)/256), dim3(256), 0, stream>>>(pooled, kvw, kvb, ng, nb, keg, vg, biasg);
    k_attn<<<dim3(NB*PH/64), dim3(256), 0, stream>>>(xh, xc, keg, vg, biasg, out);
    k_mlp_h<<<dim3(NB*PH/64), dim3(256), 0, stream>>>(out, mh_w1, mh_b1, mh_w2, mh_b2);
}

// Round 2
// 337.390 us; speedup vs baseline: 1.1014x; 1.0600x over previous
//
#include <hip/hip_runtime.h>
#include <math.h>

// Problem constants (fixed by reference: B=8, Cl=128, Ch=64, Hl=Wl=96, Hh=Wh=192, CROSS=12)
#define NB 8
#define CL 128
#define CH 64
#define HL 96
#define WL 96
#define PL (HL*WL)          // 9216
#define HH 192
#define WH 192
#define PH (HH*WH)          // 36864
#define NS 144              // CROSS*CROSS
#define BN_S 0.9999950000374997f   // 1/sqrt(1+1e-5)
#define INV12 (1.0f/12.0f)         // S^-0.5

typedef __attribute__((ext_vector_type(8))) short bf16x8;
typedef __attribute__((ext_vector_type(4))) float f32x4;
#define MFMA16(a,b,c) __builtin_amdgcn_mfma_f32_16x16x32_bf16(a,b,c,0,0,0)

__device__ __forceinline__ float gelu_exact(float x){
    return 0.5f*x*(1.0f + erff(x*0.7071067811865475f));
}
__device__ __forceinline__ short f2bf(float f){
    union { float f; unsigned u; } v; v.f = f;
    unsigned r = v.u + 0x7FFFu + ((v.u >> 16) & 1u);   // round-nearest-even
    return (short)(r >> 16);
}

// ---------------- K1: x_l2 = x_l + mlp_l(x_l)  [MFMA bf16, 64 px/block, 4 waves x 16 px] ----------
__global__ __launch_bounds__(256) void k_mlp_l(
    const float* __restrict__ xl, const float* __restrict__ w1, const float* __restrict__ b1,
    const float* __restrict__ w2, const float* __restrict__ b2, float* __restrict__ xl2)
{
    __shared__ short Wb[128*136];   // W1 then W2
    __shared__ short Xb[64*136];    // Xt then Ht
    __shared__ float bS[256];       // b1 | b2
    const int tid = threadIdx.x;
    const int b   = blockIdx.x / (PL/64);
    const int hw0 = (blockIdx.x % (PL/64)) * 64;
    const float* xb = xl + (size_t)b*CL*PL + hw0;
    #pragma unroll
    for (int i=0;i<64;i++){ int idx=i*256+tid; Wb[(idx>>7)*136 + (idx&127)] = f2bf(w1[idx]); }
    #pragma unroll
    for (int i=0;i<32;i++){ int idx=i*256+tid; int c=idx>>6, p=idx&63;
        Xb[p*136+c] = f2bf(xb[(size_t)c*PL + p]); }
    if (tid < 128) bS[tid] = b1[tid]; else bS[tid] = b2[tid-128];
    __syncthreads();
    const int w = tid>>6, lane = tid&63, l16 = lane&15, q = lane>>4;
    const int pw = w*16;
    float hv[8][4];
    #pragma unroll
    for (int mt=0; mt<8; mt++){
        f32x4 acc = {0.f,0.f,0.f,0.f};
        #pragma unroll
        for (int k=0;k<4;k++){
            bf16x8 af = *(const bf16x8*)&Wb[(mt*16+l16)*136 + k*32 + q*8];
            bf16x8 bf = *(const bf16x8*)&Xb[(pw+l16)*136 + k*32 + q*8];
            acc = MFMA16(af, bf, acc);
        }
        #pragma unroll
        for (int r=0;r<4;r++) hv[mt][r] = gelu_exact(acc[r] + bS[mt*16+q*4+r]);
    }
    #pragma unroll
    for (int mt=0;mt<8;mt++)
        #pragma unroll
        for (int r=0;r<4;r++)
            Xb[(pw+l16)*136 + mt*16+q*4+r] = f2bf(hv[mt][r]);
    __syncthreads();
    #pragma unroll
    for (int i=0;i<64;i++){ int idx=i*256+tid; Wb[(idx>>7)*136 + (idx&127)] = f2bf(w2[idx]); }
    __syncthreads();
    float* yb = xl2 + (size_t)b*CL*PL + hw0;
    #pragma unroll
    for (int mt=0; mt<8; mt++){
        f32x4 acc = {0.f,0.f,0.f,0.f};
        #pragma unroll
        for (int k=0;k<4;k++){
            bf16x8 af = *(const bf16x8*)&Wb[(mt*16+l16)*136 + k*32 + q*8];
            bf16x8 bf = *(const bf16x8*)&Xb[(pw+l16)*136 + k*32 + q*8];
            acc = MFMA16(af, bf, acc);
        }
        #pragma unroll
        for (int r=0;r<4;r++){
            int o = mt*16 + q*4 + r;
            size_t off = (size_t)o*PL + pw + l16;
            yb[off] = acc[r] + bS[128+o] + xb[off];
        }
    }
}

// ---------------- K2: xc = relu(bn(conv1x1(x_l2, conv_w)))  [MFMA bf16] ----------------
__global__ __launch_bounds__(256) void k_conv_l(
    const float* __restrict__ xl2, const float* __restrict__ cw,
    const float* __restrict__ bng, const float* __restrict__ bnb, float* __restrict__ xc)
{
    __shared__ short Wb[64*136];
    __shared__ short Xb[64*136];
    const int tid = threadIdx.x;
    const int b   = blockIdx.x / (PL/64);
    const int hw0 = (blockIdx.x % (PL/64)) * 64;
    const float* xb = xl2 + (size_t)b*CL*PL + hw0;
    #pragma unroll
    for (int i=0;i<32;i++){ int idx=i*256+tid; Wb[(idx>>7)*136 + (idx&127)] = f2bf(cw[idx]); }
    #pragma unroll
    for (int i=0;i<32;i++){ int idx=i*256+tid; int c=idx>>6, p=idx&63;
        Xb[p*136+c] = f2bf(xb[(size_t)c*PL + p]); }
    __syncthreads();
    const int w = tid>>6, lane = tid&63, l16 = lane&15, q = lane>>4;
    const int pw = w*16;
    float* yb = xc + (size_t)b*CH*PL + hw0;
    #pragma unroll
    for (int mt=0; mt<4; mt++){
        f32x4 acc = {0.f,0.f,0.f,0.f};
        #pragma unroll
        for (int k=0;k<4;k++){
            bf16x8 af = *(const bf16x8*)&Wb[(mt*16+l16)*136 + k*32 + q*8];
            bf16x8 bf = *(const bf16x8*)&Xb[(pw+l16)*136 + k*32 + q*8];
            acc = MFMA16(af, bf, acc);
        }
        #pragma unroll
        for (int r=0;r<4;r++){
            int o = mt*16 + q*4 + r;
            float sc = bng[o]*BN_S, bb = bnb[o];
            yb[(size_t)o*PL + pw + l16] = fmaxf(sc*acc[r] + bb, 0.f);
        }
    }
}

// ---------------- K4a: pooled[b,c,s] = max_{8x8}( bn_kv(x_l2) ) ----------------
__global__ __launch_bounds__(192) void k_pool(
    const float* __restrict__ xl2, const float* __restrict__ g, const float* __restrict__ bta,
    float* __restrict__ pooled)
{
    const int plane = blockIdx.x;      // b*CL + c
    const int tid = threadIdx.x;
    if (tid >= NS) return;
    const int c = plane & (CL-1);
    const float sc = g[c]*BN_S;
    const float tc = bta[c];
    const int i = tid/12, j = tid%12;
    const float* base = xl2 + (size_t)plane*PL + (size_t)i*8*WL + j*8;
    float m = -3.4e38f;
    #pragma unroll
    for (int dy=0;dy<8;dy++){
        const float* rr = base + dy*WL;
        #pragma unroll
        for (int dx=0;dx<8;dx++) m = fmaxf(m, sc*rr[dx]+tc);
    }
    pooled[(size_t)plane*NS + tid] = m;
}

// ---------------- K4b: kv proj, thread per (o,s), o in 0..127 (2*Ch=128 rows): 576 blocks --------
// keg[b][s][ch] = kv_k * ng[ch]*BN_S/12 ; biasg[b][s] += kv_k * nb[ch]/12 ; vg[b][s][ch] = kv_v
__global__ __launch_bounds__(256) void k_kv(
    const float* __restrict__ pooled, const float* __restrict__ kvw, const float* __restrict__ kvb,
    const float* __restrict__ ng, const float* __restrict__ nb,
    float* __restrict__ keg, float* __restrict__ vg, float* __restrict__ biasg)
{
    const int t = blockIdx.x*256 + threadIdx.x;     // over NB*128*NS = 147456
    const int s = t % NS;
    const int r = t / NS;
    const int o = r & 127;        // 2*Ch = 128 output rows
    const int b = r >> 7;
    const float* P = pooled + (size_t)b*CL*NS + s;
    const float* W = kvw + (size_t)o*CL;
    float acc = kvb[o];
    #pragma unroll 4
    for (int c=0;c<CL;c++) acc = fmaf(W[c], P[(size_t)c*NS], acc);
    if (o < CH){
        keg[((size_t)b*NS+s)*CH + o] = acc * (ng[o]*(BN_S*INV12));
        atomicAdd(&biasg[b*NS+s], acc * (nb[o]*INV12));
    } else {
        vg[((size_t)b*NS+s)*CH + (o-CH)] = acc;
    }
}

// ---------------- K5: cross-attention + upsample residual + mlp_h, all fused ----------------
// xh2 = xh + bilinear_up2x(xc) computed inline (never materialized);
// xh3 = xh2 + attn(bn(xh2))·V   kept entirely in registers (64ch x 64px per block);
// out = xh3 + mlp_h(xh3)        computed in-block (W1h/W2h staged into the free Pt region).
// Ownership: thread (wave w, lane) owns px = w*16+(lane&15), ch = mt*16+(lane>>4)*4+r.
// Each wave touches only LDS rows pw..pw+15 of Xb/Pt for its B-fragments -> no cross-wave
// hazard on the Xb rewrite (xh3, then Ht). Numerics bit-identical to the unfused chain.
__global__ __launch_bounds__(256) void k_attn(
    const float* __restrict__ xh, const float* __restrict__ xc,
    const float* __restrict__ keg, const float* __restrict__ vg,
    const float* __restrict__ biasg,
    const float* __restrict__ w1h, const float* __restrict__ b1h,
    const float* __restrict__ w2h, const float* __restrict__ b2h,
    float* __restrict__ out)
{
    __shared__ short KVb[64*168];   // Ke (144x72) then Vt (64x168)
    __shared__ short Xb[64*72];     // Xt (bf16 xh2) -> xh3 -> Ht
    __shared__ short Pt[64*168];    // P transposed [p][s] (pad s=144..159) -> W1h|W2h
    __shared__ float bS[NS];
    __shared__ float bH[128];       // b1h | b2h
    const int tid = threadIdx.x;
    const int b   = blockIdx.x / (PH/64);
    const int hw0 = (blockIdx.x % (PH/64)) * 64;
    const int y   = hw0 / WH;          // block-uniform output row (WH=192=3*64)
    const int xst = hw0 % WH;
    // row-side bilinear weights (block-uniform)
    const int   lyr = (y>>1) - ((y&1)^1);
    const float fy  = (y&1) ? 0.25f : 0.75f;
    const int   y0i = lyr<0?0:lyr;
    const int   y1i = (lyr+1>HL-1)?(HL-1):(lyr+1);

    const float* xb  = xh + (size_t)b*CH*PH + hw0;
    const float* xcb = xc + (size_t)b*CH*PL;
    const float* keb = keg + (size_t)b*NS*CH;

    const int w = tid>>6, lane = tid&63, l16 = lane&15, q = lane>>4;
    const int pw = w*16;
    const int px = pw + l16;

    // cooperative stages
    #pragma unroll
    for (int i=0;i<36;i++){ int idx=i*256+tid; KVb[(idx>>6)*72 + (idx&63)] = f2bf(keb[idx]); }
    if (tid < NS) bS[tid] = biasg[b*NS+tid];
    if (tid < 64) bH[tid] = b1h[tid]; else if (tid < 128) bH[tid] = b2h[tid-64];
    #pragma unroll
    for (int i=0;i<4;i++){ int idx=i*256+tid; Pt[(idx>>4)*168 + 144 + (idx&15)] = 0; }

    // ownership-aligned stage of Xt = bf16(xh + bilerp(xc)); keep fp32 residual in regs
    const int xo  = xst + px;
    const int lx  = (xo>>1) - ((xo&1)^1);
    const float fx = (xo&1) ? 0.25f : 0.75f;
    const int x0i = lx<0?0:lx;
    const int x1i = (lx+1>WL-1)?(WL-1):(lx+1);
    float resid[16];
    #pragma unroll
    for (int mt=0; mt<4; mt++)
        #pragma unroll
        for (int r=0; r<4; r++){
            int ch = mt*16 + q*4 + r;
            const float* s = xcb + (size_t)ch*PL;
            float v00 = s[y0i*WL+x0i], v01 = s[y0i*WL+x1i];
            float v10 = s[y1i*WL+x0i], v11 = s[y1i*WL+x1i];
            float top = v00 + fx*(v01-v00);
            float bot = v10 + fx*(v11-v10);
            float up  = top + fy*(bot-top);
            float val = xb[(size_t)ch*PH + px] + up;
            resid[mt*4+r] = val;
            Xb[px*72+ch] = f2bf(val);
        }
    __syncthreads();                                   // S1

    // ---- QK^T + softmax ----
    float ev[9][4];
    float mloc = -3.4e38f;
    #pragma unroll
    for (int st=0; st<9; st++){
        f32x4 acc = {0.f,0.f,0.f,0.f};
        #pragma unroll
        for (int k=0;k<2;k++){
            bf16x8 af = *(const bf16x8*)&KVb[(st*16+l16)*72 + k*32 + q*8];
            bf16x8 bf = *(const bf16x8*)&Xb[(pw+l16)*72 + k*32 + q*8];
            acc = MFMA16(af, bf, acc);
        }
        #pragma unroll
        for (int r=0;r<4;r++){
            float v = acc[r] + bS[st*16+q*4+r];
            ev[st][r] = v; mloc = fmaxf(mloc, v);
        }
    }
    mloc = fmaxf(mloc, __shfl_xor(mloc,16));
    mloc = fmaxf(mloc, __shfl_xor(mloc,32));
    float sloc = 0.f;
    #pragma unroll
    for (int st=0;st<9;st++)
        #pragma unroll
        for (int r=0;r<4;r++){ float e = __expf(ev[st][r]-mloc); ev[st][r]=e; sloc+=e; }
    sloc += __shfl_xor(sloc,16);
    sloc += __shfl_xor(sloc,32);
    const float rs = 1.f/sloc;
    #pragma unroll
    for (int st=0;st<9;st++)
        #pragma unroll
        for (int r=0;r<4;r++)
            Pt[(pw+l16)*168 + st*16+q*4+r] = f2bf(ev[st][r]);
    __syncthreads();                                   // S2: Ke reads done; Pt visible
    const float* vb = vg + (size_t)b*NS*CH;
    #pragma unroll
    for (int i=0;i<36;i++){ int idx=i*256+tid; int s=idx>>6, c=idx&63;
        KVb[c*168 + s] = f2bf(vb[idx]); }
    #pragma unroll
    for (int i=0;i<4;i++){ int idx=i*256+tid; KVb[(idx>>4)*168 + 144 + (idx&15)] = 0; }
    __syncthreads();                                   // S3: Vt visible

    // ---- PV -> xh3 in registers; rewrite Xb (own rows) with bf16(xh3) ----
    #pragma unroll
    for (int mt=0; mt<4; mt++){
        f32x4 acc = {0.f,0.f,0.f,0.f};
        #pragma unroll
        for (int k=0;k<5;k++){
            bf16x8 af = *(const bf16x8*)&KVb[(mt*16+l16)*168 + k*32 + q*8];
            bf16x8 bf = *(const bf16x8*)&Pt[(pw+l16)*168 + k*32 + q*8];
            acc = MFMA16(af, bf, acc);
        }
        #pragma unroll
        for (int r=0;r<4;r++){
            float v = resid[mt*4+r] + acc[r]*rs;       // xh3 (identical fp32 expr as before)
            resid[mt*4+r] = v;
            Xb[px*72 + mt*16+q*4+r] = f2bf(v);
        }
    }
    __syncthreads();                                   // S4: all PV Pt-reads done
    // stage W1h (Pt cols 0..71) and W2h (Pt cols 72..143)
    #pragma unroll
    for (int i=0;i<16;i++){ int idx=i*256+tid; Pt[(idx>>6)*168 + (idx&63)] = f2bf(w1h[idx]); }
    #pragma unroll
    for (int i=0;i<16;i++){ int idx=i*256+tid; Pt[(idx>>6)*168 + 72 + (idx&63)] = f2bf(w2h[idx]); }
    __syncthreads();                                   // S5: weights visible

    // ---- mlp_h: h = gelu(W1.xh3 + b1) ----
    float hv[4][4];
    #pragma unroll
    for (int mt=0; mt<4; mt++){
        f32x4 acc = {0.f,0.f,0.f,0.f};
        #pragma unroll
        for (int k=0;k<2;k++){
            bf16x8 af = *(const bf16x8*)&Pt[(mt*16+l16)*168 + k*32 + q*8];
            bf16x8 bf = *(const bf16x8*)&Xb[(pw+l16)*72 + k*32 + q*8];
            acc = MFMA16(af, bf, acc);
        }
        #pragma unroll
        for (int r=0;r<4;r++) hv[mt][r] = gelu_exact(acc[r] + bH[mt*16+q*4+r]);
    }
    // write Ht into Xb (own rows; intra-wave program order keeps reads-before-writes safe)
    #pragma unroll
    for (int mt=0;mt<4;mt++)
        #pragma unroll
        for (int r=0;r<4;r++)
            Xb[px*72 + mt*16+q*4+r] = f2bf(hv[mt][r]);

    // ---- y = xh3 + W2.h + b2 ----
    float* ob = out + (size_t)b*CH*PH + hw0;
    #pragma unroll
    for (int mt=0; mt<4; mt++){
        f32x4 acc = {0.f,0.f,0.f,0.f};
        #pragma unroll
        for (int k=0;k<2;k++){
            bf16x8 af = *(const bf16x8*)&Pt[(mt*16+l16)*168 + 72 + k*32 + q*8];
            bf16x8 bf = *(const bf16x8*)&Xb[(pw+l16)*72 + k*32 + q*8];
            acc = MFMA16(af, bf, acc);
        }
        #pragma unroll
        for (int r=0;r<4;r++){
            int ch = mt*16 + q*4 + r;
            ob[(size_t)ch*PH + px] = acc[r] + bH[64+ch] + resid[mt*4+r];
        }
    }
}

extern "C" void kernel_launch(void* const* d_in, const int* in_sizes, int n_in,
                              void* d_out, int out_size, void* d_ws, size_t ws_size,
                              hipStream_t stream)
{
    const float* xl    = (const float*)d_in[0];
    const float* xh    = (const float*)d_in[1];
    const float* ml_w1 = (const float*)d_in[2];
    const float* ml_b1 = (const float*)d_in[3];
    const float* ml_w2 = (const float*)d_in[4];
    const float* ml_b2 = (const float*)d_in[5];
    const float* cw    = (const float*)d_in[6];
    const float* cbg   = (const float*)d_in[7];
    const float* cbb   = (const float*)d_in[8];
    const float* kbg   = (const float*)d_in[9];
    const float* kbb   = (const float*)d_in[10];
    const float* kvw   = (const float*)d_in[11];
    const float* kvb   = (const float*)d_in[12];
    const float* ng    = (const float*)d_in[13];
    const float* nb    = (const float*)d_in[14];
    const float* mh_w1 = (const float*)d_in[15];
    const float* mh_b1 = (const float*)d_in[16];
    const float* mh_w2 = (const float*)d_in[17];
    const float* mh_b2 = (const float*)d_in[18];
    float* out = (float*)d_out;

    float* ws     = (float*)d_ws;
    float* xl2    = ws;                          // NB*CL*PL
    float* xc     = xl2    + (size_t)NB*CL*PL;   // NB*CH*PL
    float* pooled = xc     + (size_t)NB*CH*PL;   // NB*CL*NS
    float* keg    = pooled + (size_t)NB*CL*NS;   // NB*NS*CH
    float* vg     = keg    + (size_t)NB*NS*CH;   // NB*NS*CH
    float* biasg  = vg     + (size_t)NB*NS*CH;   // NB*NS

    k_mlp_l<<<dim3(NB*PL/64), dim3(256), 0, stream>>>(xl, ml_w1, ml_b1, ml_w2, ml_b2, xl2);
    k_conv_l<<<dim3(NB*PL/64), dim3(256), 0, stream>>>(xl2, cw, cbg, cbb, xc);
    k_pool<<<dim3(NB*CL), dim3(192), 0, stream>>>(xl2, kbg, kbb, pooled);
    hipMemsetAsync(biasg, 0, (size_t)NB*NS*sizeof(float), stream);
    k_kv<<<dim3((NB*128*NS)/256), dim3(256), 0, stream>>>(pooled, kvw, kvb, ng, nb, keg, vg, biasg);
    k_attn<<<dim3(NB*PH/64), dim3(256), 0, stream>>>(xh, xc, keg, vg, biasg,
                                                     mh_w1, mh_b1, mh_w2, mh_b2, out);
}

// Round 3
// 306.339 us; speedup vs baseline: 1.2131x; 1.1014x over previous
//
#include <hip/hip_runtime.h>
#include <math.h>

// Problem constants (fixed by reference: B=8, Cl=128, Ch=64, Hl=Wl=96, Hh=Wh=192, CROSS=12)
#define NB 8
#define CL 128
#define CH 64
#define HL 96
#define WL 96
#define PL (HL*WL)          // 9216
#define HH 192
#define WH 192
#define PH (HH*WH)          // 36864
#define NS 144              // CROSS*CROSS
#define BN_S 0.9999950000374997f   // 1/sqrt(1+1e-5)
#define INV12 (1.0f/12.0f)         // S^-0.5

typedef __attribute__((ext_vector_type(8))) short bf16x8;
typedef __attribute__((ext_vector_type(4))) float f32x4;
typedef __attribute__((ext_vector_type(2))) unsigned int uu2;
#define MFMA16(a,b,c) __builtin_amdgcn_mfma_f32_16x16x32_bf16(a,b,c,0,0,0)

__device__ __forceinline__ float gelu_exact(float x){
    return 0.5f*x*(1.0f + erff(x*0.7071067811865475f));
}
__device__ __forceinline__ short f2bf(float f){
    union { float f; unsigned u; } v; v.f = f;
    unsigned r = v.u + 0x7FFFu + ((v.u >> 16) & 1u);   // round-nearest-even
    return (short)(r >> 16);
}
// 4x f32 -> 4x bf16 (RNE, identical to f2bf) packed into one 8B LDS write
__device__ __forceinline__ void st4(short* p, float a, float b, float c, float d){
    uu2 r;
    asm("v_cvt_pk_bf16_f32 %0, %1, %2" : "=v"(r.x) : "v"(a), "v"(b));
    asm("v_cvt_pk_bf16_f32 %0, %1, %2" : "=v"(r.y) : "v"(c), "v"(d));
    *(uu2*)p = r;
}
__device__ __forceinline__ void st4v(short* p, float4 v){ st4(p, v.x, v.y, v.z, v.w); }

// ---------------- K1: xl2 = xl + mlp_l(xl); xc = relu(bn(conv1x1(xl2)))  [fused, MFMA bf16] ------
// 64 px/block, 4 waves x 16 px. Thread ownership in epilogues: px = w*16+(lane&15),
// ch = mt*16+(lane>>4)*4+r  (r=0..3 contiguous -> short4 LDS writes).
__global__ __launch_bounds__(256) void k_mlp_l(
    const float* __restrict__ xl, const float* __restrict__ w1, const float* __restrict__ b1,
    const float* __restrict__ w2, const float* __restrict__ b2,
    const float* __restrict__ cw, const float* __restrict__ bng, const float* __restrict__ bnb,
    float* __restrict__ xl2, float* __restrict__ xc)
{
    __shared__ short Wb[128*136];   // W1 -> W2 -> cw
    __shared__ short Xb[64*136];    // Xt -> Ht -> bf16(xl2)
    __shared__ float bS[256];       // b1 | b2
    __shared__ float bC[128];       // bn scale | bn bias
    const int tid = threadIdx.x;
    const int b   = blockIdx.x / (PL/64);
    const int hw0 = (blockIdx.x % (PL/64)) * 64;
    const float* xb = xl + (size_t)b*CL*PL + hw0;
    // W1 stage (128x128, float4 -> b64, conflict-free)
    #pragma unroll
    for (int i=0;i<16;i++){
        int idx4 = i*256+tid;
        int row = idx4>>5, c4 = (idx4&31)<<2;
        st4v(&Wb[row*136 + c4], *(const float4*)&w1[(row<<7) + c4]);
    }
    // X transpose stage: 4 coalesced loads per thread -> one b64 write
    {
        const int p = tid&63, wv = tid>>6;
        #pragma unroll
        for (int i=0;i<8;i++){
            int c0 = wv*4 + i*16;
            float a0 = xb[(size_t)(c0+0)*PL + p];
            float a1 = xb[(size_t)(c0+1)*PL + p];
            float a2 = xb[(size_t)(c0+2)*PL + p];
            float a3 = xb[(size_t)(c0+3)*PL + p];
            st4(&Xb[p*136 + c0], a0,a1,a2,a3);
        }
    }
    if (tid < 128) bS[tid] = b1[tid]; else bS[tid] = b2[tid-128];
    __syncthreads();                                   // S0
    const int w = tid>>6, lane = tid&63, l16 = lane&15, q = lane>>4;
    const int pw = w*16, px = pw + l16;
    float hv[8][4];
    #pragma unroll
    for (int mt=0; mt<8; mt++){
        f32x4 acc = {0.f,0.f,0.f,0.f};
        #pragma unroll
        for (int k=0;k<4;k++){
            bf16x8 af = *(const bf16x8*)&Wb[(mt*16+l16)*136 + k*32 + q*8];
            bf16x8 bf = *(const bf16x8*)&Xb[(pw+l16)*136 + k*32 + q*8];
            acc = MFMA16(af, bf, acc);
        }
        #pragma unroll
        for (int r=0;r<4;r++) hv[mt][r] = gelu_exact(acc[r] + bS[mt*16+q*4+r]);
    }
    // Ht into own rows (intra-wave program order keeps reads-before-writes safe)
    #pragma unroll
    for (int mt=0;mt<8;mt++)
        st4(&Xb[px*136 + mt*16 + q*4], hv[mt][0],hv[mt][1],hv[mt][2],hv[mt][3]);
    __syncthreads();                                   // S1: W1 reads done
    #pragma unroll
    for (int i=0;i<16;i++){
        int idx4 = i*256+tid;
        int row = idx4>>5, c4 = (idx4&31)<<2;
        st4v(&Wb[row*136 + c4], *(const float4*)&w2[(row<<7) + c4]);
    }
    __syncthreads();                                   // S2: W2 visible
    float* yb = xl2 + (size_t)b*CL*PL + hw0;
    #pragma unroll
    for (int mt=0; mt<8; mt++){
        f32x4 acc = {0.f,0.f,0.f,0.f};
        #pragma unroll
        for (int k=0;k<4;k++){
            bf16x8 af = *(const bf16x8*)&Wb[(mt*16+l16)*136 + k*32 + q*8];
            bf16x8 bf = *(const bf16x8*)&Xb[(pw+l16)*136 + k*32 + q*8];
            acc = MFMA16(af, bf, acc);
        }
        #pragma unroll
        for (int r=0;r<4;r++){
            int o = mt*16 + q*4 + r;
            size_t off = (size_t)o*PL + px;
            float yy = acc[r] + bS[128+o] + xb[off];
            yb[off] = yy;
            hv[mt][r] = yy;                            // keep xl2 tile in regs
        }
    }
    // rewrite own rows with bf16(xl2) for the conv matmul
    #pragma unroll
    for (int mt=0;mt<8;mt++)
        st4(&Xb[px*136 + mt*16 + q*4], hv[mt][0],hv[mt][1],hv[mt][2],hv[mt][3]);
    __syncthreads();                                   // S3: W2 reads done
    #pragma unroll
    for (int i=0;i<8;i++){
        int idx4 = i*256+tid;
        int row = idx4>>5, c4 = (idx4&31)<<2;
        st4v(&Wb[row*136 + c4], *(const float4*)&cw[(row<<7) + c4]);
    }
    if (tid < 64) bC[tid] = bng[tid]*BN_S; else if (tid < 128) bC[tid] = bnb[tid-64];
    __syncthreads();                                   // S4: cw visible
    float* cb = xc + (size_t)b*CH*PL + hw0;
    #pragma unroll
    for (int mt=0; mt<4; mt++){
        f32x4 acc = {0.f,0.f,0.f,0.f};
        #pragma unroll
        for (int k=0;k<4;k++){
            bf16x8 af = *(const bf16x8*)&Wb[(mt*16+l16)*136 + k*32 + q*8];
            bf16x8 bf = *(const bf16x8*)&Xb[(pw+l16)*136 + k*32 + q*8];
            acc = MFMA16(af, bf, acc);
        }
        #pragma unroll
        for (int r=0;r<4;r++){
            int o = mt*16 + q*4 + r;
            cb[(size_t)o*PL + px] = fmaxf(bC[o]*acc[r] + bC[64+o], 0.f);
        }
    }
}

// ---------------- K4a: pooled[b,c,s] = max_{8x8}( bn_kv(xl2) ) ----------------
__global__ __launch_bounds__(192) void k_pool(
    const float* __restrict__ xl2, const float* __restrict__ g, const float* __restrict__ bta,
    float* __restrict__ pooled)
{
    const int plane = blockIdx.x;      // b*CL + c
    const int tid = threadIdx.x;
    if (tid >= NS) return;
    const int c = plane & (CL-1);
    const float sc = g[c]*BN_S;
    const float tc = bta[c];
    const int i = tid/12, j = tid%12;
    const float* base = xl2 + (size_t)plane*PL + (size_t)i*8*WL + j*8;
    float m = -3.4e38f;
    #pragma unroll
    for (int dy=0;dy<8;dy++){
        const float* rr = base + dy*WL;
        #pragma unroll
        for (int dx=0;dx<8;dx++) m = fmaxf(m, sc*rr[dx]+tc);
    }
    pooled[(size_t)plane*NS + tid] = m;
}

// ---------------- K4b: kv proj. vg now written TRANSPOSED [b][ch][s] --------
// keg[b][s][ch] = kv_k * ng[ch]*BN_S/12 ; biasg[b][s] += kv_k * nb[ch]/12 ; vg[b][ch][s] = kv_v
__global__ __launch_bounds__(256) void k_kv(
    const float* __restrict__ pooled, const float* __restrict__ kvw, const float* __restrict__ kvb,
    const float* __restrict__ ng, const float* __restrict__ nb,
    float* __restrict__ keg, float* __restrict__ vg, float* __restrict__ biasg)
{
    const int t = blockIdx.x*256 + threadIdx.x;     // over NB*128*NS = 147456
    const int s = t % NS;
    const int r = t / NS;
    const int o = r & 127;        // 2*Ch = 128 output rows
    const int b = r >> 7;
    const float* P = pooled + (size_t)b*CL*NS + s;
    const float* W = kvw + (size_t)o*CL;
    float acc = kvb[o];
    #pragma unroll 4
    for (int c=0;c<CL;c++) acc = fmaf(W[c], P[(size_t)c*NS], acc);
    if (o < CH){
        keg[((size_t)b*NS+s)*CH + o] = acc * (ng[o]*(BN_S*INV12));
        atomicAdd(&biasg[b*NS+s], acc * (nb[o]*INV12));
    } else {
        vg[((size_t)b*CH + (o-CH))*NS + s] = acc;   // transposed: [b][ch][s]
    }
}

// ---------------- K5: cross-attention + upsample residual + mlp_h, all fused ----------------
// xh2 = xh + bilinear_up2x(xc) computed inline; xh3 = xh2 + attn(bn(xh2))·V in registers;
// out = xh3 + mlp_h(xh3) in-block. All cooperative staging is float4->cvt_pk->b64 (conflict-free);
// all ownership LDS writes are short4-packed.
__global__ __launch_bounds__(256) void k_attn(
    const float* __restrict__ xh, const float* __restrict__ xc,
    const float* __restrict__ keg, const float* __restrict__ vg,
    const float* __restrict__ biasg,
    const float* __restrict__ w1h, const float* __restrict__ b1h,
    const float* __restrict__ w2h, const float* __restrict__ b2h,
    float* __restrict__ out)
{
    __shared__ short KVb[64*168];   // Ke (144x72) then Vt (64x168)
    __shared__ short Xb[64*72];     // Xt (bf16 xh2) -> xh3 -> Ht
    __shared__ short Pt[64*168];    // P transposed [p][s] (pad s=144..159) -> W1h|W2h
    __shared__ float bS[NS];
    __shared__ float bH[128];       // b1h | b2h
    const int tid = threadIdx.x;
    const int b   = blockIdx.x / (PH/64);
    const int hw0 = (blockIdx.x % (PH/64)) * 64;
    const int y   = hw0 / WH;          // block-uniform output row (WH=192=3*64)
    const int xst = hw0 % WH;
    const int   lyr = (y>>1) - ((y&1)^1);
    const float fy  = (y&1) ? 0.25f : 0.75f;
    const int   y0i = lyr<0?0:lyr;
    const int   y1i = (lyr+1>HL-1)?(HL-1):(lyr+1);

    const float* xb  = xh + (size_t)b*CH*PH + hw0;
    const float* xcb = xc + (size_t)b*CH*PL;
    const float* keb = keg + (size_t)b*NS*CH;

    const int w = tid>>6, lane = tid&63, l16 = lane&15, q = lane>>4;
    const int pw = w*16, px = pw + l16;

    // Ke stage: [s][ch] linear copy, 2304 float4
    #pragma unroll
    for (int i=0;i<9;i++){
        int idx4 = i*256+tid;
        int s = idx4>>4, c4 = (idx4&15)<<2;
        st4v(&KVb[s*72 + c4], *(const float4*)&keb[(s<<6) + c4]);
    }
    if (tid < NS) bS[tid] = biasg[b*NS+tid];
    if (tid < 64) bH[tid] = b1h[tid]; else if (tid < 128) bH[tid] = b2h[tid-64];
    { int row = tid>>2, o4 = (tid&3)<<2;                 // Pt pad cols 144..159 = 0
      *(uu2*)&Pt[row*168 + 144 + o4] = (uu2){0u,0u}; }

    // ownership-aligned stage of Xt = bf16(xh + bilerp(xc)); fp32 residual kept in regs
    const int xo  = xst + px;
    const int lx  = (xo>>1) - ((xo&1)^1);
    const float fx = (xo&1) ? 0.25f : 0.75f;
    const int x0i = lx<0?0:lx;
    const int x1i = (lx+1>WL-1)?(WL-1):(lx+1);
    float resid[16];
    #pragma unroll
    for (int mt=0; mt<4; mt++){
        #pragma unroll
        for (int r=0; r<4; r++){
            int ch = mt*16 + q*4 + r;
            const float* s = xcb + (size_t)ch*PL;
            float v00 = s[y0i*WL+x0i], v01 = s[y0i*WL+x1i];
            float v10 = s[y1i*WL+x0i], v11 = s[y1i*WL+x1i];
            float top = v00 + fx*(v01-v00);
            float bot = v10 + fx*(v11-v10);
            float up  = top + fy*(bot-top);
            resid[mt*4+r] = xb[(size_t)ch*PH + px] + up;
        }
        st4(&Xb[px*72 + mt*16 + q*4],
            resid[mt*4+0], resid[mt*4+1], resid[mt*4+2], resid[mt*4+3]);
    }
    __syncthreads();                                   // S1

    // ---- QK^T + softmax ----
    float ev[9][4];
    float mloc = -3.4e38f;
    #pragma unroll
    for (int st=0; st<9; st++){
        f32x4 acc = {0.f,0.f,0.f,0.f};
        #pragma unroll
        for (int k=0;k<2;k++){
            bf16x8 af = *(const bf16x8*)&KVb[(st*16+l16)*72 + k*32 + q*8];
            bf16x8 bf = *(const bf16x8*)&Xb[(pw+l16)*72 + k*32 + q*8];
            acc = MFMA16(af, bf, acc);
        }
        #pragma unroll
        for (int r=0;r<4;r++){
            float v = acc[r] + bS[st*16+q*4+r];
            ev[st][r] = v; mloc = fmaxf(mloc, v);
        }
    }
    mloc = fmaxf(mloc, __shfl_xor(mloc,16));
    mloc = fmaxf(mloc, __shfl_xor(mloc,32));
    float sloc = 0.f;
    #pragma unroll
    for (int st=0;st<9;st++)
        #pragma unroll
        for (int r=0;r<4;r++){ float e = __expf(ev[st][r]-mloc); ev[st][r]=e; sloc+=e; }
    sloc += __shfl_xor(sloc,16);
    sloc += __shfl_xor(sloc,32);
    const float rs = 1.f/sloc;
    #pragma unroll
    for (int st=0;st<9;st++)
        st4(&Pt[px*168 + st*16 + q*4], ev[st][0], ev[st][1], ev[st][2], ev[st][3]);
    __syncthreads();                                   // S2: Ke reads done; Pt visible
    // Vt stage from transposed vg [b][ch][s]: linear copy, 2304 float4
    const float* vb = vg + (size_t)b*CH*NS;
    #pragma unroll
    for (int i=0;i<9;i++){
        int idx4 = i*256+tid;
        int c = idx4/36, s4 = (idx4 - c*36)<<2;
        st4v(&KVb[c*168 + s4], *(const float4*)&vb[c*NS + s4]);
    }
    { int row = tid>>2, o4 = (tid&3)<<2;                 // KVb pad cols 144..159 = 0
      *(uu2*)&KVb[row*168 + 144 + o4] = (uu2){0u,0u}; }
    __syncthreads();                                   // S3: Vt visible

    // ---- PV -> xh3 in registers; rewrite Xb (own rows) with bf16(xh3) ----
    #pragma unroll
    for (int mt=0; mt<4; mt++){
        f32x4 acc = {0.f,0.f,0.f,0.f};
        #pragma unroll
        for (int k=0;k<5;k++){
            bf16x8 af = *(const bf16x8*)&KVb[(mt*16+l16)*168 + k*32 + q*8];
            bf16x8 bf = *(const bf16x8*)&Pt[(pw+l16)*168 + k*32 + q*8];
            acc = MFMA16(af, bf, acc);
        }
        #pragma unroll
        for (int r=0;r<4;r++)
            resid[mt*4+r] = resid[mt*4+r] + acc[r]*rs;   // xh3
        st4(&Xb[px*72 + mt*16 + q*4],
            resid[mt*4+0], resid[mt*4+1], resid[mt*4+2], resid[mt*4+3]);
    }
    __syncthreads();                                   // S4: all PV Pt-reads done
    // stage W1h (Pt cols 0..71) and W2h (Pt cols 72..143)
    #pragma unroll
    for (int i=0;i<4;i++){
        int idx4 = i*256+tid;
        int o = idx4>>4, c4 = (idx4&15)<<2;
        st4v(&Pt[o*168 + c4], *(const float4*)&w1h[(o<<6) + c4]);
    }
    #pragma unroll
    for (int i=0;i<4;i++){
        int idx4 = i*256+tid;
        int o = idx4>>4, c4 = (idx4&15)<<2;
        st4v(&Pt[o*168 + 72 + c4], *(const float4*)&w2h[(o<<6) + c4]);
    }
    __syncthreads();                                   // S5: weights visible

    // ---- mlp_h: h = gelu(W1.xh3 + b1) ----
    float hv[4][4];
    #pragma unroll
    for (int mt=0; mt<4; mt++){
        f32x4 acc = {0.f,0.f,0.f,0.f};
        #pragma unroll
        for (int k=0;k<2;k++){
            bf16x8 af = *(const bf16x8*)&Pt[(mt*16+l16)*168 + k*32 + q*8];
            bf16x8 bf = *(const bf16x8*)&Xb[(pw+l16)*72 + k*32 + q*8];
            acc = MFMA16(af, bf, acc);
        }
        #pragma unroll
        for (int r=0;r<4;r++) hv[mt][r] = gelu_exact(acc[r] + bH[mt*16+q*4+r]);
    }
    #pragma unroll
    for (int mt=0;mt<4;mt++)
        st4(&Xb[px*72 + mt*16 + q*4], hv[mt][0], hv[mt][1], hv[mt][2], hv[mt][3]);

    // ---- y = xh3 + W2.h + b2 ----
    float* ob = out + (size_t)b*CH*PH + hw0;
    #pragma unroll
    for (int mt=0; mt<4; mt++){
        f32x4 acc = {0.f,0.f,0.f,0.f};
        #pragma unroll
        for (int k=0;k<2;k++){
            bf16x8 af = *(const bf16x8*)&Pt[(mt*16+l16)*168 + 72 + k*32 + q*8];
            bf16x8 bf = *(const bf16x8*)&Xb[(pw+l16)*72 + k*32 + q*8];
            acc = MFMA16(af, bf, acc);
        }
        #pragma unroll
        for (int r=0;r<4;r++){
            int ch = mt*16 + q*4 + r;
            ob[(size_t)ch*PH + px] = acc[r] + bH[64+ch] + resid[mt*4+r];
        }
    }
}

extern "C" void kernel_launch(void* const* d_in, const int* in_sizes, int n_in,
                              void* d_out, int out_size, void* d_ws, size_t ws_size,
                              hipStream_t stream)
{
    const float* xl    = (const float*)d_in[0];
    const float* xh    = (const float*)d_in[1];
    const float* ml_w1 = (const float*)d_in[2];
    const float* ml_b1 = (const float*)d_in[3];
    const float* ml_w2 = (const float*)d_in[4];
    const float* ml_b2 = (const float*)d_in[5];
    const float* cw    = (const float*)d_in[6];
    const float* cbg   = (const float*)d_in[7];
    const float* cbb   = (const float*)d_in[8];
    const float* kbg   = (const float*)d_in[9];
    const float* kbb   = (const float*)d_in[10];
    const float* kvw   = (const float*)d_in[11];
    const float* kvb   = (const float*)d_in[12];
    const float* ng    = (const float*)d_in[13];
    const float* nb    = (const float*)d_in[14];
    const float* mh_w1 = (const float*)d_in[15];
    const float* mh_b1 = (const float*)d_in[16];
    const float* mh_w2 = (const float*)d_in[17];
    const float* mh_b2 = (const float*)d_in[18];
    float* out = (float*)d_out;

    float* ws     = (float*)d_ws;
    float* xl2    = ws;                          // NB*CL*PL
    float* xc     = xl2    + (size_t)NB*CL*PL;   // NB*CH*PL
    float* pooled = xc     + (size_t)NB*CH*PL;   // NB*CL*NS
    float* keg    = pooled + (size_t)NB*CL*NS;   // NB*NS*CH
    float* vg     = keg    + (size_t)NB*NS*CH;   // NB*CH*NS (transposed)
    float* biasg  = vg     + (size_t)NB*NS*CH;   // NB*NS

    k_mlp_l<<<dim3(NB*PL/64), dim3(256), 0, stream>>>(xl, ml_w1, ml_b1, ml_w2, ml_b2,
                                                      cw, cbg, cbb, xl2, xc);
    k_pool<<<dim3(NB*CL), dim3(192), 0, stream>>>(xl2, kbg, kbb, pooled);
    hipMemsetAsync(biasg, 0, (size_t)NB*NS*sizeof(float), stream);
    k_kv<<<dim3((NB*128*NS)/256), dim3(256), 0, stream>>>(pooled, kvw, kvb, ng, nb, keg, vg, biasg);
    k_attn<<<dim3(NB*PH/64), dim3(256), 0, stream>>>(xh, xc, keg, vg, biasg,
                                                     mh_w1, mh_b1, mh_w2, mh_b2, out);
}